// Round 1
// baseline (5012.576 us; speedup 1.0000x reference)
//
#include <hip/hip_runtime.h>
#include <hip/hip_fp16.h>

#define T_DIM 512
#define B_DIM 64
#define I_DIM 512
#define H_DIM 512
#define BH (B_DIM * H_DIM)              // 32768
#define TBH ((size_t)T_DIM * BH)        // 16777216

typedef __attribute__((ext_vector_type(8))) short short8;
typedef __attribute__((ext_vector_type(4))) float f32x4;

// LDS swizzle for 16x512 ushort planes: keeps 8-ushort (16B) blocks intact,
// spreads banks evenly across rows for both MFMA-frag and gate access.
#define SW16(r, k) ((r) * 512 + ((k) ^ (((r) & 15) << 3)))

__device__ __forceinline__ unsigned short f2bf(float x) {
    unsigned int u = __float_as_uint(x);
    u = u + 0x7FFFu + ((u >> 16) & 1u);
    return (unsigned short)(u >> 16);
}
__device__ __forceinline__ float bf2f(unsigned short s) {
    return __uint_as_float(((unsigned int)s) << 16);
}

// --- inline-asm memory helpers -------------------------------------------
// coherent (device-scope) 16B load: bypasses L1+L2 per-access, NO flushes
__device__ __forceinline__ void ld128_coh(uint4& d, const void* p) {
    asm volatile("global_load_dwordx4 %0, %1, off sc0 sc1"
                 : "=v"(d) : "v"(p) : "memory");
}
// plain cached loads (cross-dispatch data: xn, xz/xr)
__device__ __forceinline__ void ld32f(float& d, const void* p) {
    asm volatile("global_load_dword %0, %1, off" : "=v"(d) : "v"(p));
}
__device__ __forceinline__ void ld32u(unsigned int& d, const void* p) {
    asm volatile("global_load_dword %0, %1, off" : "=v"(d) : "v"(p));
}

// ---------------------------------------------------------------------------
// Kernel X: xz/xr input projections -> packed f16 pair per (t,b).
// Also zeroes the flag array (runs before rnn on the same stream).
// ---------------------------------------------------------------------------
__global__ __launch_bounds__(256) void xzr_kernel(
    const float* __restrict__ input,
    const float* __restrict__ zw, const float* __restrict__ zb,
    const float* __restrict__ rw, const float* __restrict__ rb,
    unsigned int* __restrict__ xzr, unsigned int* __restrict__ flags)
{
    const int tid = threadIdx.x, bx = blockIdx.x;
    if (bx == 0 && tid < 32) flags[tid] = 0u;
    const int row = bx * 4 + (tid >> 6);
    const int lane = tid & 63;
    const float* p = input + (size_t)row * I_DIM + lane * 8;
    float x[8], z[8], r[8];
    *(float4*)(x)     = *(const float4*)(p);
    *(float4*)(x + 4) = *(const float4*)(p + 4);
    *(float4*)(z)     = *(const float4*)(zw + lane * 8);
    *(float4*)(z + 4) = *(const float4*)(zw + lane * 8 + 4);
    *(float4*)(r)     = *(const float4*)(rw + lane * 8);
    *(float4*)(r + 4) = *(const float4*)(rw + lane * 8 + 4);
    float pz = 0.f, pr = 0.f;
#pragma unroll
    for (int i = 0; i < 8; i++) { pz += x[i] * z[i]; pr += x[i] * r[i]; }
#pragma unroll
    for (int off = 32; off > 0; off >>= 1) {
        pz += __shfl_xor(pz, off);
        pr += __shfl_xor(pr, off);
    }
    if (lane == 0) {
        unsigned int uz = __half_as_ushort(__float2half(pz + zb[0]));
        unsigned int ur = __half_as_ushort(__float2half(pr + rb[0]));
        xzr[row] = (uz << 16) | ur;
    }
}

// ---------------------------------------------------------------------------
// Kernel A: xn = input @ h_w_w^T + h_w_b -> d_out[0..TBH)
// ---------------------------------------------------------------------------
#define APITCH 40

__global__ __launch_bounds__(256, 2) void xn_gemm_kernel(
    const float* __restrict__ A, const float* __restrict__ W,
    const float* __restrict__ bias, float* __restrict__ C)
{
    __shared__ __align__(16) unsigned short a_hi[64 * APITCH], a_lo[64 * APITCH];
    __shared__ __align__(16) unsigned short b_hi[64 * APITCH], b_lo[64 * APITCH];
    const int tid = threadIdx.x;
    const int bx = blockIdx.x;
    const int mt = bx >> 3, ntile = bx & 7;
    const int wv = tid >> 6, lane = tid & 63;
    const int srow = tid >> 2, skseg = (tid & 3) * 8;
    const int m = lane & 15;
    const int ko = (lane >> 4) * 8;

    f32x4 ahh[4], ahl[4], alh[4];
#pragma unroll
    for (int i = 0; i < 4; i++) { ahh[i] = (f32x4)0.f; ahl[i] = (f32x4)0.f; alh[i] = (f32x4)0.f; }

    for (int kt = 0; kt < 16; ++kt) {
        {
            float fa[8], fb[8];
            const float* pa = A + (size_t)(mt * 64 + srow) * I_DIM + kt * 32 + skseg;
            *(float4*)(fa)     = *(const float4*)(pa);
            *(float4*)(fa + 4) = *(const float4*)(pa + 4);
            const float* pb = W + (size_t)(ntile * 64 + srow) * I_DIM + kt * 32 + skseg;
            *(float4*)(fb)     = *(const float4*)(pb);
            *(float4*)(fb + 4) = *(const float4*)(pb + 4);
            short8 hi, lo;
#pragma unroll
            for (int i = 0; i < 8; i++) {
                unsigned short h = f2bf(fa[i]);
                hi[i] = (short)h; lo[i] = (short)f2bf(fa[i] - bf2f(h));
            }
            *(short8*)&a_hi[srow * APITCH + skseg] = hi;
            *(short8*)&a_lo[srow * APITCH + skseg] = lo;
#pragma unroll
            for (int i = 0; i < 8; i++) {
                unsigned short h = f2bf(fb[i]);
                hi[i] = (short)h; lo[i] = (short)f2bf(fb[i] - bf2f(h));
            }
            *(short8*)&b_hi[srow * APITCH + skseg] = hi;
            *(short8*)&b_lo[srow * APITCH + skseg] = lo;
        }
        __syncthreads();
        short8 vah = *(const short8*)&a_hi[(wv * 16 + m) * APITCH + ko];
        short8 val = *(const short8*)&a_lo[(wv * 16 + m) * APITCH + ko];
#pragma unroll
        for (int ns = 0; ns < 4; ++ns) {
            short8 vbh = *(const short8*)&b_hi[(ns * 16 + m) * APITCH + ko];
            short8 vbl = *(const short8*)&b_lo[(ns * 16 + m) * APITCH + ko];
            ahh[ns] = __builtin_amdgcn_mfma_f32_16x16x32_bf16(vah, vbh, ahh[ns], 0, 0, 0);
            ahl[ns] = __builtin_amdgcn_mfma_f32_16x16x32_bf16(vah, vbl, ahl[ns], 0, 0, 0);
            alh[ns] = __builtin_amdgcn_mfma_f32_16x16x32_bf16(val, vbh, alh[ns], 0, 0, 0);
        }
        __syncthreads();
    }
#pragma unroll
    for (int ns = 0; ns < 4; ++ns) {
#pragma unroll
        for (int rr = 0; rr < 4; ++rr) {
            int rowd = wv * 16 + (lane >> 4) * 4 + rr;
            int cold = ntile * 64 + ns * 16 + (lane & 15);
            float v = ahh[ns][rr] + ahl[ns][rr] + alh[ns][rr] + bias[cold];
            C[(size_t)(mt * 64 + rowd) * H_DIM + cold] = v;
        }
    }
}

// ---------------------------------------------------------------------------
// Recurrent persistent kernel. 16 WGs = 2 teams x 8 col slices. Each WG owns
// ONE 64-col weight slice (128 VGPRs of bf16 hi/lo frags) and TWO independent
// batch groups (16 rows each), processed in alternating slots A/B. While
// group A's publish drains / propagates / is reloaded, group B's gates+MFMA
// execute — the cross-WG exchange latency (the old 10.5k-cycle step's
// dominant cost) is hidden under the other group's compute. h is exchanged
// as one packed (hi<<16)|lo uint32 per element, relaxed agent scope.
// NOTE: every __syncthreads drains vmcnt, so next-slot loads are issued
// immediately AFTER the unpack barrier: gates+MFMA (~1.2k cyc) cover their
// latency before the pre-epilogue barrier's implicit drain.
// ---------------------------------------------------------------------------
__global__ __launch_bounds__(256, 1) void rnn_kernel(
    const float* __restrict__ h0,
    const unsigned int* __restrict__ xzr,
    const float* __restrict__ zuw, const float* __restrict__ ruw,
    const float* __restrict__ zub, const float* __restrict__ rub,
    const float* __restrict__ huw, const float* __restrict__ hub,
    float* __restrict__ out,
    unsigned int* __restrict__ xbuf32, unsigned int* __restrict__ flags)
{
    __shared__ __align__(16) unsigned short hs_hi[2][16 * 512], hs_lo[2][16 * 512];
    __shared__ float zu[512], ru[512];
    __shared__ float zg[2][16], rg[2][16];

    const int tid = threadIdx.x;
    const int bid = blockIdx.x;
    const int js = bid & 7;
    const int gA = (bid >> 3) * 2, gB = gA + 1;   // two batch groups per WG
    const int wv = tid >> 6, lane = tid & 63;
    const int quad = lane >> 4, am = lane & 15;
    const int col = js * 64 + wv * 16 + am;
    const int ko = quad * 8;
    const int gr = tid >> 4, gs = tid & 15;
    // unpack/load mapping: row = tid&15 (stride-512 rows -> ~2-way LDS banks
    // after SW16), 32-elem col chunk per thread; global side still coalesces
    // (16 rows x 128B contiguous segments per wave).
    const int lrow = tid & 15, lcolb = (tid >> 4) * 32;

    for (int i = tid; i < 512; i += 256) { zu[i] = zuw[i]; ru[i] = ruw[i]; }
    const float zbias = zub[0], rbias = rub[0];
    const float hubl = hub[col];

    // persistent recurrent weights: bf16 hi/lo B-fragments (128 VGPRs),
    // shared by BOTH groups — this is what makes 2 groups/WG free.
    short8 wh[16], wl[16];
#pragma unroll
    for (int kt = 0; kt < 16; ++kt) {
        float f[8];
        const float* p = huw + (size_t)col * H_DIM + kt * 32 + ko;
        *(float4*)(f)     = *(const float4*)(p);
        *(float4*)(f + 4) = *(const float4*)(p + 4);
#pragma unroll
        for (int i = 0; i < 8; i++) {
            unsigned short h = f2bf(f[i]);
            wh[kt][i] = (short)h;
            wl[kt][i] = (short)f2bf(f[i] - bf2f(h));
        }
    }

    // init LDS with packed h0 for both groups
#pragma unroll
    for (int G = 0; G < 2; ++G) {
        const int g = gA + G;
        unsigned short* Hh = hs_hi[G];
        unsigned short* Hl = hs_lo[G];
#pragma unroll
        for (int i = 0; i < 8; i++) {
            int idx = tid * 4 + i * 1024;
            int row = idx >> 9, k = idx & 511;
            float4 f = *(const float4*)(h0 + (size_t)(g * 16 + row) * H_DIM + k);
            float fa[4] = {f.x, f.y, f.z, f.w};
            unsigned int h_[4], l_[4];
#pragma unroll
            for (int j = 0; j < 4; j++) {
                h_[j] = f2bf(fa[j]);
                l_[j] = f2bf(fa[j] - bf2f((unsigned short)h_[j]));
            }
            int a = SW16(row, k);
            uint2 hv = { h_[0] | (h_[1] << 16), h_[2] | (h_[3] << 16) };
            uint2 lv = { l_[0] | (l_[1] << 16), l_[2] | (l_[3] << 16) };
            *(uint2*)&Hh[a] = hv;
            *(uint2*)&Hl[a] = lv;
        }
    }
    float hkA[4], hkB[4];
#pragma unroll
    for (int rr = 0; rr < 4; ++rr) {
        hkA[rr] = h0[(size_t)(gA * 16 + quad * 4 + rr) * H_DIM + col];
        hkB[rr] = h0[(size_t)(gB * 16 + quad * 4 + rr) * H_DIM + col];
    }

    uint4 vA[8], vB[8];           // staged packed-h for the next A / B slot
    float xnA[4], xnB[4];
    unsigned int zrwA = 0, zrwB = 0;
    {   // prefetch xn/xzr for slot A, t=0
        const float* xp = out + (size_t)(gA * 16 + quad * 4) * H_DIM + col;
        ld32f(xnA[0], xp);             ld32f(xnA[1], xp + H_DIM);
        ld32f(xnA[2], xp + 2 * H_DIM); ld32f(xnA[3], xp + 3 * H_DIM);
        ld32u(zrwA, xzr + gA * 16 + gr);
    }
    __syncthreads();

    // One slot = one (group, timestep). L = LDS plane (0 for gA, 1 for gB).
    auto slot = [&](int L, int gc, int gn, int t,
                    bool unpack, bool issuev, bool issuex,
                    int pollmin, int vbuf, int txn,
                    uint4 (&vc)[8], uint4 (&vn)[8],
                    float (&hk)[4], float (&xnc)[4], float (&xnn)[4],
                    unsigned int& zrwc, unsigned int& zrwn)
    {
        unsigned short* Hh = hs_hi[L];
        unsigned short* Hl = hs_lo[L];
        float* zgp = zg[L];
        float* rgp = rg[L];

        // regs loaded last slot were drained by its barriers; tie gate regs
        // so the compiler cannot float their uses above, and fence so the
        // vc-unpack VALU cannot hoist above the wait (guide rule #18).
        asm volatile("s_waitcnt vmcnt(0)"
                     : "+v"(xnc[0]), "+v"(xnc[1]), "+v"(xnc[2]), "+v"(xnc[3]),
                       "+v"(zrwc)
                     :: "memory");
        __builtin_amdgcn_sched_barrier(0);

        // --- unpack staged packed h_{t-1}(gc) -> LDS plane L --------------
        if (unpack) {
#pragma unroll
            for (int p = 0; p < 4; ++p) {
                uint4 a = vc[2 * p], b = vc[2 * p + 1];
                short8 h8, l8;
                h8[0] = (short)(a.x >> 16); h8[1] = (short)(a.y >> 16);
                h8[2] = (short)(a.z >> 16); h8[3] = (short)(a.w >> 16);
                h8[4] = (short)(b.x >> 16); h8[5] = (short)(b.y >> 16);
                h8[6] = (short)(b.z >> 16); h8[7] = (short)(b.w >> 16);
                l8[0] = (short)(a.x & 0xFFFFu); l8[1] = (short)(a.y & 0xFFFFu);
                l8[2] = (short)(a.z & 0xFFFFu); l8[3] = (short)(a.w & 0xFFFFu);
                l8[4] = (short)(b.x & 0xFFFFu); l8[5] = (short)(b.y & 0xFFFFu);
                l8[6] = (short)(b.z & 0xFFFFu); l8[7] = (short)(b.w & 0xFFFFu);
                const int c = lcolb + p * 8;
                *(short8*)&Hh[SW16(lrow, c)] = h8;
                *(short8*)&Hl[SW16(lrow, c)] = l8;
            }
        }
        __syncthreads();                  // plane L visible; nothing in flight

        // --- poll + issue next slot's loads (fly under gates+MFMA) --------
        if (issuev) {
            if (lane < 8) {
                const unsigned int* fp = flags + gn * 8 + lane;
                while (__hip_atomic_load(fp, __ATOMIC_RELAXED,
                                         __HIP_MEMORY_SCOPE_AGENT)
                       < (unsigned int)pollmin)
                    __builtin_amdgcn_s_sleep(1);
            }
            const char* src = (const char*)xbuf32 +
                ((size_t)(vbuf * 4 + gn) * 8192 + lrow * 512 + lcolb) * 4;
#pragma unroll
            for (int i = 0; i < 8; i++) ld128_coh(vn[i], src + i * 16);
        }
        if (issuex) {
            const float* xp = out + (size_t)txn * BH +
                              (size_t)(gn * 16 + quad * 4) * H_DIM + col;
            ld32f(xnn[0], xp);             ld32f(xnn[1], xp + H_DIM);
            ld32f(xnn[2], xp + 2 * H_DIM); ld32f(xnn[3], xp + 3 * H_DIM);
            ld32u(zrwn, xzr + txn * B_DIM + gn * 16 + gr);
        }

        // --- gates (b128 LDS reads) ---------------------------------------
        float pz = 0.f, pr = 0.f;
#pragma unroll
        for (int i = 0; i < 4; i++) {
            const int k = gs * 8 + i * 128;
            const int a = SW16(gr, k);
            short8 hw = *(const short8*)&Hh[a];
            short8 lw = *(const short8*)&Hl[a];
            float4 z0 = *(const float4*)&zu[k], z1 = *(const float4*)&zu[k + 4];
            float4 r0 = *(const float4*)&ru[k], r1 = *(const float4*)&ru[k + 4];
            float zs[8] = {z0.x, z0.y, z0.z, z0.w, z1.x, z1.y, z1.z, z1.w};
            float rs[8] = {r0.x, r0.y, r0.z, r0.w, r1.x, r1.y, r1.z, r1.w};
#pragma unroll
            for (int j = 0; j < 8; j++) {
                float hf = bf2f((unsigned short)hw[j]) + bf2f((unsigned short)lw[j]);
                pz += hf * zs[j];
                pr += hf * rs[j];
            }
        }
#pragma unroll
        for (int off = 8; off > 0; off >>= 1) {
            pz += __shfl_xor(pz, off);
            pr += __shfl_xor(pr, off);
        }
        if (gs == 0) {
            float xzf = __half2float(__ushort_as_half((unsigned short)(zrwc >> 16)));
            float xrf = __half2float(__ushort_as_half((unsigned short)(zrwc & 0xFFFFu)));
            zgp[gr] = 1.f / (1.f + __expf(-(xzf + pz + zbias)));
            rgp[gr] = 1.f / (1.f + __expf(-(xrf + pr + rbias)));
        }

        // --- h @ h_u_w^T slice (bf16x3, frags direct from LDS) ------------
        f32x4 hh = (f32x4)0.f, hl = (f32x4)0.f, lh = (f32x4)0.f;
#pragma unroll
        for (int kt = 0; kt < 16; ++kt) {
            short8 ah = *(const short8*)&Hh[SW16(am, kt * 32 + ko)];
            short8 al = *(const short8*)&Hl[SW16(am, kt * 32 + ko)];
            hh = __builtin_amdgcn_mfma_f32_16x16x32_bf16(ah, wh[kt], hh, 0, 0, 0);
            hl = __builtin_amdgcn_mfma_f32_16x16x32_bf16(ah, wl[kt], hl, 0, 0, 0);
            lh = __builtin_amdgcn_mfma_f32_16x16x32_bf16(al, wh[kt], lh, 0, 0, 0);
        }
        __syncthreads();   // zg/rg visible; implicit drain covers our loads

        // --- epilogue + packed uint32 publish (relaxed agent) -------------
        unsigned int* xb = xbuf32 + (size_t)((t & 1) * 4 + gc) * 8192;
        float* op = out + (size_t)t * BH;
#pragma unroll
        for (int rr = 0; rr < 4; ++rr) {
            const int rl = quad * 4 + rr;
            float gemm = hh[rr] + hl[rr] + lh[rr] + hubl;
            float x2 = xnc[rr] + gemm * rgp[rl];
            x2 = fminf(fmaxf(x2, -30.f), 30.f);
            float e = __expf(2.f * x2);
            float ntv = (e - 1.f) / (e + 1.f);
            float hv = (1.f - zgp[rl]) * ntv + zgp[rl] * hk[rr];
            op[(size_t)(gc * 16 + rl) * H_DIM + col] = hv;
            unsigned short hu = f2bf(hv);
            unsigned short lu = f2bf(hv - bf2f(hu));
            __hip_atomic_store(&xb[rl * 512 + col],
                               ((unsigned int)hu << 16) | (unsigned int)lu,
                               __ATOMIC_RELAXED, __HIP_MEMORY_SCOPE_AGENT);
            hk[rr] = hv;
        }
        asm volatile("s_waitcnt vmcnt(0)" ::: "memory");  // this wave drained
        __syncthreads();                                   // all waves drained
        if (tid == 0)
            __hip_atomic_store(&flags[gc * 8 + js], (unsigned int)(t + 1),
                               __ATOMIC_RELAXED, __HIP_MEMORY_SCOPE_AGENT);
    };

    for (int t = 0; t < T_DIM; ++t) {
        // slot A: consume h_{t-1}(gA); stage vB for B(t) (needs flags[gB]>=t,
        // published to buf (t-1)&1) and xn(gB,t).
        slot(0, gA, gB, t,
             t > 0, t > 0, true,
             t, (t + 1) & 1, t,
             vA, vB, hkA, xnA, xnB, zrwA, zrwB);
        // slot B: consume h_{t-1}(gB); stage vA for A(t+1) (needs
        // flags[gA]>=t+1, published to buf t&1) and xn(gA,t+1).
        const bool nl = (t < T_DIM - 1);
        slot(1, gB, gA, t,
             t > 0, nl, nl,
             t + 1, t & 1, t + 1,
             vB, vA, hkB, xnB, xnA, zrwB, zrwA);
    }

    // hidden_final
#pragma unroll
    for (int rr = 0; rr < 4; ++rr) {
        out[TBH + (size_t)(gA * 16 + quad * 4 + rr) * H_DIM + col] = hkA[rr];
        out[TBH + (size_t)(gB * 16 + quad * 4 + rr) * H_DIM + col] = hkB[rr];
    }
}

extern "C" void kernel_launch(void* const* d_in, const int* in_sizes, int n_in,
                              void* d_out, int out_size, void* d_ws, size_t ws_size,
                              hipStream_t stream)
{
    const float* input  = (const float*)d_in[0];
    const float* hidden = (const float*)d_in[1];
    const float* zt_w_w = (const float*)d_in[2];
    const float* zt_w_b = (const float*)d_in[3];
    const float* zt_u_w = (const float*)d_in[4];
    const float* zt_u_b = (const float*)d_in[5];
    const float* rt_w_w = (const float*)d_in[6];
    const float* rt_w_b = (const float*)d_in[7];
    const float* rt_u_w = (const float*)d_in[8];
    const float* rt_u_b = (const float*)d_in[9];
    const float* h_w_w  = (const float*)d_in[10];
    const float* h_w_b  = (const float*)d_in[11];
    const float* h_u_w  = (const float*)d_in[12];
    const float* h_u_b  = (const float*)d_in[13];
    float* out = (float*)d_out;

    // ws: [0,4K) flags | [4K, 4K+256K) xbuf (2 slots x 4 groups x 32KB packed
    // uint32) | [+, +128K) packed f16 xz/xr.  Total 388KB.
    unsigned int* flags = (unsigned int*)d_ws;
    unsigned int* xbuf32 = (unsigned int*)((char*)d_ws + 4096);
    unsigned int* xzr = (unsigned int*)((char*)d_ws + 4096 + 262144);

    xzr_kernel<<<dim3(8192), dim3(256), 0, stream>>>(input, zt_w_w, zt_w_b,
                                                     rt_w_w, rt_w_b, xzr, flags);
    xn_gemm_kernel<<<dim3(4096), dim3(256), 0, stream>>>(input, h_w_w, h_w_b, out);
    rnn_kernel<<<dim3(16), dim3(256), 0, stream>>>(hidden, xzr, zt_u_w, rt_u_w,
                                                   zt_u_b, rt_u_b, h_u_w, h_u_b,
                                                   out, xbuf32, flags);
}

// Round 8
// 2382.000 us; speedup vs baseline: 2.1044x; 2.1044x over previous
//
#include <hip/hip_runtime.h>
#include <hip/hip_fp16.h>

#define T_DIM 512
#define B_DIM 64
#define I_DIM 512
#define H_DIM 512
#define BH (B_DIM * H_DIM)              // 32768
#define TBH ((size_t)T_DIM * BH)        // 16777216

typedef __attribute__((ext_vector_type(8))) short short8;
typedef __attribute__((ext_vector_type(4))) float f32x4;

// LDS swizzle for 16x512 ushort planes: keeps 8-ushort (16B) blocks intact,
// spreads banks evenly across rows for both MFMA-frag and gate access.
#define SW16(r, k) ((r) * 512 + ((k) ^ (((r) & 15) << 3)))

__device__ __forceinline__ unsigned short f2bf(float x) {
    unsigned int u = __float_as_uint(x);
    u = u + 0x7FFFu + ((u >> 16) & 1u);
    return (unsigned short)(u >> 16);
}
__device__ __forceinline__ float bf2f(unsigned short s) {
    return __uint_as_float(((unsigned int)s) << 16);
}

// --- inline-asm memory helpers (round-0 proven set, unchanged) ------------
// coherent (device-scope) 16B load: bypasses L1+L2 per-access, NO flushes
__device__ __forceinline__ void ld128_coh(uint4& d, const void* p) {
    asm volatile("global_load_dwordx4 %0, %1, off sc0 sc1"
                 : "=v"(d) : "v"(p) : "memory");
}
// same, but drains ALL outstanding vector loads afterwards (vmcnt counts
// the whole wave's queue). NOTE: gfx950 inline asm rejects tied 128-bit
// operands, so the waitcnt must live inside a load asm, not standalone.
__device__ __forceinline__ void ld128_coh_wait(uint4& d, const void* p) {
    asm volatile("global_load_dwordx4 %0, %1, off sc0 sc1\n\t"
                 "s_waitcnt vmcnt(0)"
                 : "=v"(d) : "v"(p) : "memory");
}
// plain cached loads (cross-dispatch data: xn, xz/xr)
__device__ __forceinline__ void ld32f(float& d, const void* p) {
    asm volatile("global_load_dword %0, %1, off" : "=v"(d) : "v"(p));
}
__device__ __forceinline__ void ld32u(unsigned int& d, const void* p) {
    asm volatile("global_load_dword %0, %1, off" : "=v"(d) : "v"(p));
}

// ---------------------------------------------------------------------------
// Kernel X: xz/xr input projections -> packed f16 pair per (t,b).
// Also zeroes the flag array (runs before rnn on the same stream).
// ---------------------------------------------------------------------------
__global__ __launch_bounds__(256) void xzr_kernel(
    const float* __restrict__ input,
    const float* __restrict__ zw, const float* __restrict__ zb,
    const float* __restrict__ rw, const float* __restrict__ rb,
    unsigned int* __restrict__ xzr, unsigned int* __restrict__ flags)
{
    const int tid = threadIdx.x, bx = blockIdx.x;
    if (bx == 0 && tid < 32) flags[tid] = 0u;
    const int row = bx * 4 + (tid >> 6);
    const int lane = tid & 63;
    const float* p = input + (size_t)row * I_DIM + lane * 8;
    float x[8], z[8], r[8];
    *(float4*)(x)     = *(const float4*)(p);
    *(float4*)(x + 4) = *(const float4*)(p + 4);
    *(float4*)(z)     = *(const float4*)(zw + lane * 8);
    *(float4*)(z + 4) = *(const float4*)(zw + lane * 8 + 4);
    *(float4*)(r)     = *(const float4*)(rw + lane * 8);
    *(float4*)(r + 4) = *(const float4*)(rw + lane * 8 + 4);
    float pz = 0.f, pr = 0.f;
#pragma unroll
    for (int i = 0; i < 8; i++) { pz += x[i] * z[i]; pr += x[i] * r[i]; }
#pragma unroll
    for (int off = 32; off > 0; off >>= 1) {
        pz += __shfl_xor(pz, off);
        pr += __shfl_xor(pr, off);
    }
    if (lane == 0) {
        unsigned int uz = __half_as_ushort(__float2half(pz + zb[0]));
        unsigned int ur = __half_as_ushort(__float2half(pr + rb[0]));
        xzr[row] = (uz << 16) | ur;
    }
}

// ---------------------------------------------------------------------------
// Kernel A: xn = input @ h_w_w^T + h_w_b -> d_out[0..TBH)
// ---------------------------------------------------------------------------
#define APITCH 40

__global__ __launch_bounds__(256, 2) void xn_gemm_kernel(
    const float* __restrict__ A, const float* __restrict__ W,
    const float* __restrict__ bias, float* __restrict__ C)
{
    __shared__ __align__(16) unsigned short a_hi[64 * APITCH], a_lo[64 * APITCH];
    __shared__ __align__(16) unsigned short b_hi[64 * APITCH], b_lo[64 * APITCH];
    const int tid = threadIdx.x;
    const int bx = blockIdx.x;
    const int mt = bx >> 3, ntile = bx & 7;
    const int wv = tid >> 6, lane = tid & 63;
    const int srow = tid >> 2, skseg = (tid & 3) * 8;
    const int m = lane & 15;
    const int ko = (lane >> 4) * 8;

    f32x4 ahh[4], ahl[4], alh[4];
#pragma unroll
    for (int i = 0; i < 4; i++) { ahh[i] = (f32x4)0.f; ahl[i] = (f32x4)0.f; alh[i] = (f32x4)0.f; }

    for (int kt = 0; kt < 16; ++kt) {
        {
            float fa[8], fb[8];
            const float* pa = A + (size_t)(mt * 64 + srow) * I_DIM + kt * 32 + skseg;
            *(float4*)(fa)     = *(const float4*)(pa);
            *(float4*)(fa + 4) = *(const float4*)(pa + 4);
            const float* pb = W + (size_t)(ntile * 64 + srow) * I_DIM + kt * 32 + skseg;
            *(float4*)(fb)     = *(const float4*)(pb);
            *(float4*)(fb + 4) = *(const float4*)(pb + 4);
            short8 hi, lo;
#pragma unroll
            for (int i = 0; i < 8; i++) {
                unsigned short h = f2bf(fa[i]);
                hi[i] = (short)h; lo[i] = (short)f2bf(fa[i] - bf2f(h));
            }
            *(short8*)&a_hi[srow * APITCH + skseg] = hi;
            *(short8*)&a_lo[srow * APITCH + skseg] = lo;
#pragma unroll
            for (int i = 0; i < 8; i++) {
                unsigned short h = f2bf(fb[i]);
                hi[i] = (short)h; lo[i] = (short)f2bf(fb[i] - bf2f(h));
            }
            *(short8*)&b_hi[srow * APITCH + skseg] = hi;
            *(short8*)&b_lo[srow * APITCH + skseg] = lo;
        }
        __syncthreads();
        short8 vah = *(const short8*)&a_hi[(wv * 16 + m) * APITCH + ko];
        short8 val = *(const short8*)&a_lo[(wv * 16 + m) * APITCH + ko];
#pragma unroll
        for (int ns = 0; ns < 4; ++ns) {
            short8 vbh = *(const short8*)&b_hi[(ns * 16 + m) * APITCH + ko];
            short8 vbl = *(const short8*)&b_lo[(ns * 16 + m) * APITCH + ko];
            ahh[ns] = __builtin_amdgcn_mfma_f32_16x16x32_bf16(vah, vbh, ahh[ns], 0, 0, 0);
            ahl[ns] = __builtin_amdgcn_mfma_f32_16x16x32_bf16(vah, vbl, ahl[ns], 0, 0, 0);
            alh[ns] = __builtin_amdgcn_mfma_f32_16x16x32_bf16(val, vbh, alh[ns], 0, 0, 0);
        }
        __syncthreads();
    }
#pragma unroll
    for (int ns = 0; ns < 4; ++ns) {
#pragma unroll
        for (int rr = 0; rr < 4; ++rr) {
            int rowd = wv * 16 + (lane >> 4) * 4 + rr;
            int cold = ntile * 64 + ns * 16 + (lane & 15);
            float v = ahh[ns][rr] + ahl[ns][rr] + alh[ns][rr] + bias[cold];
            C[(size_t)(mt * 64 + rowd) * H_DIM + cold] = v;
        }
    }
}

// ---------------------------------------------------------------------------
// Recurrent persistent kernel — ROUND-0 skeleton with the EXCHANGE PROTOCOL
// BYTE-IDENTICAL (32 WGs = 4 groups x 8 slices; LDS h planes; 2B atomic
// publishes; per-WG flags with value t+1; lanes<8 poll; batched sc0sc1
// reload). Two WAVE-LOCAL deltas only:
//   (1) Gates by MFMA: one extra persistent B-frag set wg[16] with cols
//       {0:zu_hi, 1:ru_hi, 2:zu_lo, 3:ru_lo}; two extra accumulator chains
//       ga=mfma(ah,wg), gb=mfma(al,wg) reuse the SAME A-frags the main GEMM
//       loads. col0+col2 sums = (hi+lo)(zhi+zlo) = full-precision h.zu.
//       Gate logits land in-register (D[row][gatecol], row=quad*4+rr at lane
//       quad*16+col) and are broadcast with 4 shfls/row. This deletes the
//       whole gate LDS/VALU phase, the shuffle reduce, zg/rg LDS, and one
//       of the three per-step barriers. No cross-WG data added.
//   (2) out-stores moved AFTER the flag: the 4 HBM writes no longer sit
//       under the publish vmcnt(0) drain; they drain under the next poll.
// ---------------------------------------------------------------------------
__global__ __launch_bounds__(256, 1) void rnn_kernel(
    const float* __restrict__ h0,
    const unsigned int* __restrict__ xzr,
    const float* __restrict__ zuw, const float* __restrict__ ruw,
    const float* __restrict__ zub, const float* __restrict__ rub,
    const float* __restrict__ huw, const float* __restrict__ hub,
    float* __restrict__ out,
    char* __restrict__ xbuf, unsigned int* __restrict__ flags)
{
    __shared__ __align__(16) unsigned short hs_hi[16 * 512], hs_lo[16 * 512];

    const int tid = threadIdx.x;
    const int bid = blockIdx.x;
    const int g = bid >> 3, js = bid & 7;
    const int wv = tid >> 6, lane = tid & 63;
    const int quad = lane >> 4, am = lane & 15;
    const int col = js * 64 + wv * 16 + am;
    const int ko = quad * 8;

    const float zbias = zub[0], rbias = rub[0];
    const float hubl = hub[col];

    // persistent recurrent weights: bf16 hi/lo B-fragments (128 VGPRs)
    short8 wh[16], wl[16];
#pragma unroll
    for (int kt = 0; kt < 16; ++kt) {
        float f[8];
        const float* p = huw + (size_t)col * H_DIM + kt * 32 + ko;
        *(float4*)(f)     = *(const float4*)(p);
        *(float4*)(f + 4) = *(const float4*)(p + 4);
#pragma unroll
        for (int i = 0; i < 8; i++) {
            unsigned short h = f2bf(f[i]);
            wh[kt][i] = (short)h;
            wl[kt][i] = (short)f2bf(f[i] - bf2f(h));
        }
    }
    // gate B-fragments (64 VGPRs): lane holds B[col=am][k=kt*32+ko .. +7]
    // with col0=zu_hi, col1=ru_hi, col2=zu_lo, col3=ru_lo, cols>=4 zero.
    short8 wg[16];
    {
        const float* gsrc = (am & 1) ? ruw : zuw;
#pragma unroll
        for (int kt = 0; kt < 16; ++kt) {
            float f[8];
            *(float4*)(f)     = *(const float4*)(gsrc + kt * 32 + ko);
            *(float4*)(f + 4) = *(const float4*)(gsrc + kt * 32 + ko + 4);
            short8 v;
#pragma unroll
            for (int i = 0; i < 8; i++) {
                unsigned short h = f2bf(f[i]);
                unsigned short l = f2bf(f[i] - bf2f(h));
                unsigned short sel = (am < 2) ? h : l;
                v[i] = (am < 4) ? (short)sel : (short)0;
            }
            wg[kt] = v;
        }
    }

    // init LDS with packed h0 (round-0 verbatim)
#pragma unroll
    for (int i = 0; i < 8; i++) {
        int idx = tid * 4 + i * 1024;
        int row = idx >> 9, k = idx & 511;
        float4 f = *(const float4*)(h0 + (size_t)(g * 16 + row) * H_DIM + k);
        float fa[4] = {f.x, f.y, f.z, f.w};
        unsigned int h_[4], l_[4];
#pragma unroll
        for (int j = 0; j < 4; j++) {
            h_[j] = f2bf(fa[j]);
            l_[j] = f2bf(fa[j] - bf2f((unsigned short)h_[j]));
        }
        int a = SW16(row, k);
        uint2 hv = { h_[0] | (h_[1] << 16), h_[2] | (h_[3] << 16) };
        uint2 lv = { l_[0] | (l_[1] << 16), l_[2] | (l_[3] << 16) };
        *(uint2*)&hs_hi[a] = hv;
        *(uint2*)&hs_lo[a] = lv;
    }
    float hkeep[4];
#pragma unroll
    for (int rr = 0; rr < 4; ++rr)
        hkeep[rr] = h0[(size_t)(g * 16 + quad * 4 + rr) * H_DIM + col];
    __syncthreads();

    // prefetch registers for step t: xn (4 rows) + packed xz/xr word.
    // zrw is loaded per lane for row (lane&15) so gates can shfl from lane rl.
    float xnv0, xnv1, xnv2, xnv3;
    unsigned int zrw;
#define PREFETCH(tt) do {                                                     \
        const float* xp_ = out + (size_t)(tt) * BH +                          \
                           (size_t)(g * 16 + quad * 4) * H_DIM + col;         \
        ld32f(xnv0, xp_);        ld32f(xnv1, xp_ + H_DIM);                    \
        ld32f(xnv2, xp_ + 2 * H_DIM); ld32f(xnv3, xp_ + 3 * H_DIM);           \
        ld32u(zrw, xzr + (tt) * B_DIM + g * 16 + (lane & 15));                \
    } while (0)
    PREFETCH(0);

    for (int t = 0; t < T_DIM; ++t) {
        // --- tie: pin prefetched regs below the wait (rule #18) -----------
        asm volatile("s_waitcnt vmcnt(0)"
                     : "+v"(xnv0), "+v"(xnv1), "+v"(xnv2), "+v"(xnv3), "+v"(zrw)
                     :: "memory");
        __builtin_amdgcn_sched_barrier(0);

        // --- fused MFMA: h@h_u_w^T (3 chains) + gate logits (2 chains) ----
        f32x4 hh = (f32x4)0.f, hl = (f32x4)0.f, lh = (f32x4)0.f;
        f32x4 ga = (f32x4)0.f, gb = (f32x4)0.f;
#pragma unroll
        for (int kt = 0; kt < 16; ++kt) {
            short8 ah = *(const short8*)&hs_hi[SW16(am, kt * 32 + ko)];
            short8 al = *(const short8*)&hs_lo[SW16(am, kt * 32 + ko)];
            hh = __builtin_amdgcn_mfma_f32_16x16x32_bf16(ah, wh[kt], hh, 0, 0, 0);
            hl = __builtin_amdgcn_mfma_f32_16x16x32_bf16(ah, wl[kt], hl, 0, 0, 0);
            lh = __builtin_amdgcn_mfma_f32_16x16x32_bf16(al, wh[kt], lh, 0, 0, 0);
            ga = __builtin_amdgcn_mfma_f32_16x16x32_bf16(ah, wg[kt], ga, 0, 0, 0);
            gb = __builtin_amdgcn_mfma_f32_16x16x32_bf16(al, wg[kt], gb, 0, 0, 0);
        }

        // --- gates in-register: D[rl][c] lives at lane quad*16+c ----------
        float zg4[4], rg4[4];
#pragma unroll
        for (int rr = 0; rr < 4; ++rr) {
            float gv = ga[rr] + gb[rr];
            float zsum = __shfl(gv, quad * 16 + 0) + __shfl(gv, quad * 16 + 2);
            float rsum = __shfl(gv, quad * 16 + 1) + __shfl(gv, quad * 16 + 3);
            unsigned int zw_ = (unsigned int)__shfl((int)zrw, quad * 4 + rr);
            float xzf = __half2float(__ushort_as_half((unsigned short)(zw_ >> 16)));
            float xrf = __half2float(__ushort_as_half((unsigned short)(zw_ & 0xFFFFu)));
            zg4[rr] = 1.f / (1.f + __expf(-(xzf + zsum + zbias)));
            rg4[rr] = 1.f / (1.f + __expf(-(xrf + rsum + rbias)));
        }

        // --- epilogue: h_t + packed publish (publish-only under drain) ----
        float xn_a[4] = {xnv0, xnv1, xnv2, xnv3};
        char* xb = xbuf + ((size_t)(((t & 1) * 4) + g)) * 32768;
        unsigned short* bhp = (unsigned short*)xb;
        unsigned short* blp = (unsigned short*)(xb + 16384);
        float hva[4];
#pragma unroll
        for (int rr = 0; rr < 4; ++rr) {
            int rl = quad * 4 + rr;
            float gemm = hh[rr] + hl[rr] + lh[rr] + hubl;
            float x2 = xn_a[rr] + gemm * rg4[rr];
            x2 = fminf(fmaxf(x2, -30.f), 30.f);
            float e = __expf(2.f * x2);
            float ntv = (e - 1.f) / (e + 1.f);
            float hv = (1.f - zg4[rr]) * ntv + zg4[rr] * hkeep[rr];
            unsigned short hu = f2bf(hv);
            unsigned short lu = f2bf(hv - bf2f(hu));
            __hip_atomic_store(&bhp[rl * 512 + col], hu, __ATOMIC_RELAXED, __HIP_MEMORY_SCOPE_AGENT);
            __hip_atomic_store(&blp[rl * 512 + col], lu, __ATOMIC_RELAXED, __HIP_MEMORY_SCOPE_AGENT);
            hva[rr] = hv;
            hkeep[rr] = hv;
        }
        asm volatile("s_waitcnt vmcnt(0)" ::: "memory");  // drain this wave's stores
        __syncthreads();                                   // all waves drained
        if (tid == 0)
            __hip_atomic_store(&flags[g * 8 + js], (unsigned int)(t + 1),
                               __ATOMIC_RELAXED, __HIP_MEMORY_SCOPE_AGENT);

        // --- out writes off the exchange critical path --------------------
        {
            float* op = out + (size_t)t * BH;
#pragma unroll
            for (int rr = 0; rr < 4; ++rr)
                op[(size_t)(g * 16 + quad * 4 + rr) * H_DIM + col] = hva[rr];
        }
        if (t == T_DIM - 1) break;

        // --- prefetch next step's xn/xzr (hides under the spin) -----------
        PREFETCH(t + 1);

        // --- H: lane-parallel relaxed flag poll (round-0) -----------------
        if (lane < 8) {
            const unsigned int* fp = flags + g * 8 + lane;
            while (__hip_atomic_load(fp, __ATOMIC_RELAXED, __HIP_MEMORY_SCOPE_AGENT)
                   < (unsigned int)(t + 1))
                __builtin_amdgcn_s_sleep(1);
        }

        // --- J: batched coherent load of packed h_t -> LDS (round-0) ------
        const char* src = xbuf + ((size_t)(((t & 1) * 4) + g)) * 32768 + tid * 16;
        uint4 v[8];
#pragma unroll
        for (int i = 0; i < 7; i++) ld128_coh(v[i], src + i * 4096);
        ld128_coh_wait(v[7], src + 7 * 4096);  // drains all 8 (vmcnt counts the queue)
#pragma unroll
        for (int i = 0; i < 8; i++) {
            int usidx = tid * 8 + (i & 3) * 2048;
            int row = usidx >> 9, ku = usidx & 511;
            unsigned short* dst = (i < 4) ? hs_hi : hs_lo;
            *(uint4*)&dst[SW16(row, ku)] = v[i];
        }
        __syncthreads();
    }

    // hidden_final
#pragma unroll
    for (int rr = 0; rr < 4; ++rr)
        out[TBH + (size_t)(g * 16 + quad * 4 + rr) * H_DIM + col] = hkeep[rr];
#undef PREFETCH
}

extern "C" void kernel_launch(void* const* d_in, const int* in_sizes, int n_in,
                              void* d_out, int out_size, void* d_ws, size_t ws_size,
                              hipStream_t stream)
{
    const float* input  = (const float*)d_in[0];
    const float* hidden = (const float*)d_in[1];
    const float* zt_w_w = (const float*)d_in[2];
    const float* zt_w_b = (const float*)d_in[3];
    const float* zt_u_w = (const float*)d_in[4];
    const float* zt_u_b = (const float*)d_in[5];
    const float* rt_w_w = (const float*)d_in[6];
    const float* rt_w_b = (const float*)d_in[7];
    const float* rt_u_w = (const float*)d_in[8];
    const float* rt_u_b = (const float*)d_in[9];
    const float* h_w_w  = (const float*)d_in[10];
    const float* h_w_b  = (const float*)d_in[11];
    const float* h_u_w  = (const float*)d_in[12];
    const float* h_u_b  = (const float*)d_in[13];
    float* out = (float*)d_out;

    // ws: [0,4K) flags | [4K, 4K+256K) xbuf (2 slots x 4 groups x 32KB)
    //     | [+, +128K) packed f16 xz/xr.  Total 388KB.  (round-0 layout)
    unsigned int* flags = (unsigned int*)d_ws;
    char* xbuf = (char*)d_ws + 4096;
    unsigned int* xzr = (unsigned int*)((char*)d_ws + 4096 + 262144);

    xzr_kernel<<<dim3(8192), dim3(256), 0, stream>>>(input, zt_w_w, zt_w_b,
                                                     rt_w_w, rt_w_b, xzr, flags);
    xn_gemm_kernel<<<dim3(4096), dim3(256), 0, stream>>>(input, h_w_w, h_w_b, out);
    rnn_kernel<<<dim3(32), dim3(256), 0, stream>>>(hidden, xzr, zt_u_w, rt_u_w,
                                                   zt_u_b, rt_u_b, h_u_w, h_u_b,
                                                   out, xbuf, flags);
}